// Round 1
// baseline (380.032 us; speedup 1.0000x reference)
//
#include <hip/hip_runtime.h>

#define N    8192
#define DT   768
#define DO   512
#define BM   128
#define BN   128
#define TI   (N / BM)   // 64
#define TJ   (N / BN)   // 64

typedef __attribute__((ext_vector_type(8))) short   short8;   // 8 bf16 = 4 VGPRs
typedef __attribute__((ext_vector_type(4))) float   floatx4;

// round-to-nearest-even fp32 -> bf16
__device__ inline unsigned short f2bf(float x) {
    union { float f; unsigned int u; } v; v.f = x;
    unsigned int r = v.u + 0x7fffu + ((v.u >> 16) & 1u);
    return (unsigned short)(r >> 16);
}

// async global->LDS, 16B per lane (global_load_lds_dwordx4)
__device__ inline void gl2lds16(const unsigned short* g, unsigned short* l) {
    __builtin_amdgcn_global_load_lds(
        (const __attribute__((address_space(1))) unsigned int*)(const void*)g,
        (__attribute__((address_space(3))) unsigned int*)(void*)l,
        16, 0, 0);
}

// ---------------- row-normalize fp32 -> bf16 ----------------
__global__ void norm_kernel(const float* __restrict__ X,
                            unsigned short* __restrict__ Xn, int D) {
    const int row = blockIdx.x;
    const float* xr = X + (size_t)row * D;
    float ss = 0.0f;
    for (int c = threadIdx.x; c < D; c += 256) { float v = xr[c]; ss += v * v; }
    #pragma unroll
    for (int m = 32; m >= 1; m >>= 1) ss += __shfl_xor(ss, m);
    __shared__ float wsh[4];
    const int w = threadIdx.x >> 6, lane = threadIdx.x & 63;
    if (lane == 0) wsh[w] = ss;
    __syncthreads();
    const float tot = wsh[0] + wsh[1] + wsh[2] + wsh[3];
    const float scale = 1.0f / fmaxf(sqrtf(tot), 1e-8f);
    unsigned short* outr = Xn + (size_t)row * D;
    for (int c = threadIdx.x; c < D; c += 256) outr[c] = f2bf(xr[c] * scale);
}

__global__ void init_kernel(float* out) {
    if (threadIdx.x == 0) out[0] = 0.0f;
}

// ---------------- fused dual-GEMM + softmax-stat tile kernel ----------------
// partials layout: [TJ][N][4] floats  (Zt, Zo, V, U) per (jblock,row)
__launch_bounds__(256, 2)
__global__ void fused_kernel(const unsigned short* __restrict__ Xt,
                             const unsigned short* __restrict__ Xo,
                             float* __restrict__ partials) {
    __shared__ unsigned short sA[BM * 32];
    __shared__ unsigned short sB[BN * 32];
    __shared__ float wsum[2][BM][4];

    const int t    = threadIdx.x;
    const int lane = t & 63;
    const int w    = t >> 6;
    const int wm   = w >> 1, wn = w & 1;
    const int lr   = lane & 15, lg = lane >> 4;

    // XCD-friendly swizzle: bid%8 picks j within a group of 8 -> each XCD keeps
    // one B-stripe hot in its L2 while streaming A-stripes.
    const int bid = blockIdx.x;
    const int tj  = (bid & 7) | ((bid >> 9) << 3);
    const int ti  = (bid >> 3) & 63;
    const int i0  = ti * BM, j0 = tj * BN;

    floatx4 acc_t[4][4], acc_o[4][4];
    #pragma unroll
    for (int a = 0; a < 4; ++a)
        #pragma unroll
        for (int b = 0; b < 4; ++b) {
            acc_t[a][b] = (floatx4){0.0f, 0.0f, 0.0f, 0.0f};
            acc_o[a][b] = (floatx4){0.0f, 0.0f, 0.0f, 0.0f};
        }

    // ---- teacher GEMM: S_t tile, K = DT ----
    for (int k = 0; k < DT; k += 32) {
        #pragma unroll
        for (int h = 0; h < 2; ++h) {
            const int idx = t + h * 256;        // 0..511, contiguous-in-lane per wave
            const int r   = idx >> 2;
            const int c   = (idx & 3) << 3;
            gl2lds16(Xt + (size_t)(i0 + r) * DT + k + c, &sA[idx * 8]);
            gl2lds16(Xt + (size_t)(j0 + r) * DT + k + c, &sB[idx * 8]);
        }
        asm volatile("s_waitcnt vmcnt(0)" ::: "memory");
        __syncthreads();
        short8 af[4], bf[4];
        #pragma unroll
        for (int mi = 0; mi < 4; ++mi)
            af[mi] = *(const short8*)&sA[(wm * 64 + mi * 16 + lr) * 32 + lg * 8];
        #pragma unroll
        for (int ni = 0; ni < 4; ++ni)
            bf[ni] = *(const short8*)&sB[(wn * 64 + ni * 16 + lr) * 32 + lg * 8];
        #pragma unroll
        for (int mi = 0; mi < 4; ++mi)
            #pragma unroll
            for (int ni = 0; ni < 4; ++ni)
                acc_t[mi][ni] = __builtin_amdgcn_mfma_f32_16x16x32_bf16(
                    af[mi], bf[ni], acc_t[mi][ni], 0, 0, 0);
        __syncthreads();
    }

    // ---- student GEMM: S_o tile, K = DO ----
    for (int k = 0; k < DO; k += 32) {
        #pragma unroll
        for (int h = 0; h < 2; ++h) {
            const int idx = t + h * 256;
            const int r   = idx >> 2;
            const int c   = (idx & 3) << 3;
            gl2lds16(Xo + (size_t)(i0 + r) * DO + k + c, &sA[idx * 8]);
            gl2lds16(Xo + (size_t)(j0 + r) * DO + k + c, &sB[idx * 8]);
        }
        asm volatile("s_waitcnt vmcnt(0)" ::: "memory");
        __syncthreads();
        short8 af[4], bf[4];
        #pragma unroll
        for (int mi = 0; mi < 4; ++mi)
            af[mi] = *(const short8*)&sA[(wm * 64 + mi * 16 + lr) * 32 + lg * 8];
        #pragma unroll
        for (int ni = 0; ni < 4; ++ni)
            bf[ni] = *(const short8*)&sB[(wn * 64 + ni * 16 + lr) * 32 + lg * 8];
        #pragma unroll
        for (int mi = 0; mi < 4; ++mi)
            #pragma unroll
            for (int ni = 0; ni < 4; ++ni)
                acc_o[mi][ni] = __builtin_amdgcn_mfma_f32_16x16x32_bf16(
                    af[mi], bf[ni], acc_o[mi][ni], 0, 0, 0);
        __syncthreads();
    }

    // ---- fused epilogue: per-row {Zt, Zo, V, U} over this tile's 128 columns ----
    // C/D layout (verified m89/m91): col = lane&15, row = (lane>>4)*4 + reg
    #pragma unroll
    for (int mi = 0; mi < 4; ++mi) {
        #pragma unroll
        for (int r = 0; r < 4; ++r) {
            float zt = 0.0f, zo = 0.0f, vv = 0.0f, uu = 0.0f;
            const int gi = i0 + wm * 64 + mi * 16 + lg * 4 + r;
            #pragma unroll
            for (int ni = 0; ni < 4; ++ni) {
                const float a = acc_t[mi][ni][r];
                const float b = acc_o[mi][ni][r];
                const int gj = j0 + wn * 64 + ni * 16 + lr;
                float ea = __expf(a - 1.0f);
                float eb = __expf(b - 1.0f);
                if (gi == gj) { ea = 0.0f; eb = 0.0f; }   // diagonal: NEG_FILL -> prob 0
                const float e3 = ea * ea * ea;
                zt += ea; zo += eb; vv += e3; uu += e3 * (a - b);
            }
            // reduce across the 16 lanes sharing this row (lane bits 0..3)
            #pragma unroll
            for (int m = 8; m >= 1; m >>= 1) {
                zt += __shfl_xor(zt, m);
                zo += __shfl_xor(zo, m);
                vv += __shfl_xor(vv, m);
                uu += __shfl_xor(uu, m);
            }
            if (lr == 0) {
                const int row = wm * 64 + mi * 16 + lg * 4 + r;
                wsum[wn][row][0] = zt;
                wsum[wn][row][1] = zo;
                wsum[wn][row][2] = vv;
                wsum[wn][row][3] = uu;
            }
        }
    }
    __syncthreads();
    for (int x = t; x < BM * 4; x += 256) {
        const int row = x >> 2, q = x & 3;
        partials[((size_t)tj * N + (i0 + row)) * 4 + q] =
            wsum[0][row][q] + wsum[1][row][q];
    }
}

// ---------------- final per-row combine + scalar reduce ----------------
__global__ void reduce_kernel(const float* __restrict__ partials,
                              float* __restrict__ out) {
    const int i = blockIdx.x * 256 + threadIdx.x;   // row
    float zt = 0.0f, zo = 0.0f, vv = 0.0f, uu = 0.0f;
    for (int jb = 0; jb < TJ; ++jb) {
        const floatx4 q = *(const floatx4*)(partials + ((size_t)jb * N + i) * 4);
        zt += q[0]; zo += q[1]; vv += q[2]; uu += q[3];
    }
    // loss_i = (U + V*log(Zo/Zt)) / Zt^3
    float li = (uu + vv * __logf(zo / zt)) / (zt * zt * zt);
    #pragma unroll
    for (int m = 32; m >= 1; m >>= 1) li += __shfl_xor(li, m);
    __shared__ float wsh[4];
    const int w = threadIdx.x >> 6;
    if ((threadIdx.x & 63) == 0) wsh[w] = li;
    __syncthreads();
    if (threadIdx.x == 0) {
        const float s = (wsh[0] + wsh[1] + wsh[2] + wsh[3]) *
                        (1.0f / ((float)N * (float)N));   // WEIGHT=1, mean over N^2
        atomicAdd(out, s);
    }
}

extern "C" void kernel_launch(void* const* d_in, const int* in_sizes, int n_in,
                              void* d_out, int out_size, void* d_ws, size_t ws_size,
                              hipStream_t stream) {
    (void)in_sizes; (void)n_in; (void)out_size; (void)ws_size;
    const float* mo = (const float*)d_in[0];   // model_output [8192,512] fp32
    const float* tg = (const float*)d_in[1];   // targets      [8192,768] fp32
    float* out = (float*)d_out;

    char* ws = (char*)d_ws;
    unsigned short* Xt = (unsigned short*)ws;                          // 8192*768 bf16
    unsigned short* Xo = (unsigned short*)(ws + (size_t)N * DT * 2);   // 8192*512 bf16
    float* partials    = (float*)(ws + (size_t)N * DT * 2 + (size_t)N * DO * 2);
    // total ws use: 12.6 MB + 8.4 MB + 8.4 MB = 29.4 MB

    norm_kernel<<<N, 256, 0, stream>>>(tg, Xt, DT);
    norm_kernel<<<N, 256, 0, stream>>>(mo, Xo, DO);
    init_kernel<<<1, 64, 0, stream>>>(out);
    fused_kernel<<<TI * TJ, 256, 0, stream>>>(Xt, Xo, partials);
    reduce_kernel<<<N / 256, 256, 0, stream>>>(partials, out);
}

// Round 2
// 359.322 us; speedup vs baseline: 1.0576x; 1.0576x over previous
//
#include <hip/hip_runtime.h>

#define N    8192
#define DT   768
#define DO   512
#define BM   128
#define BN   128
#define TI   (N / BM)   // 64
#define TJ   (N / BN)   // 64

typedef __attribute__((ext_vector_type(8))) short   short8;   // 8 bf16 = 4 VGPRs
typedef __attribute__((ext_vector_type(4))) float   floatx4;

struct alignas(8) us4 { unsigned short x[4]; };

// round-to-nearest-even fp32 -> bf16
__device__ inline unsigned short f2bf(float x) {
    union { float f; unsigned int u; } v; v.f = x;
    unsigned int r = v.u + 0x7fffu + ((v.u >> 16) & 1u);
    return (unsigned short)(r >> 16);
}
__device__ inline float bf2f(unsigned short u) {
    union { unsigned int u; float f; } v; v.u = ((unsigned int)u) << 16;
    return v.f;
}

// async global->LDS, 16B per lane (global_load_lds_dwordx4)
__device__ inline void gl2lds16(const unsigned short* g, unsigned short* l) {
    __builtin_amdgcn_global_load_lds(
        (const __attribute__((address_space(1))) unsigned int*)(const void*)g,
        (__attribute__((address_space(3))) unsigned int*)(void*)l,
        16, 0, 0);
}

// stage one 128x32 A-tile and B-tile (bf16) into LDS via global_load_lds
template <int D>
__device__ inline void stage_tile(const unsigned short* __restrict__ Xi,
                                  const unsigned short* __restrict__ Xj,
                                  unsigned short* sA, unsigned short* sB,
                                  int i0, int j0, int k, int t) {
    #pragma unroll
    for (int h = 0; h < 2; ++h) {
        const int idx = t + h * 256;        // 0..511; lane-contiguous per wave
        const int r   = idx >> 2;
        const int c   = (idx & 3) << 3;
        gl2lds16(Xi + (size_t)(i0 + r) * D + k + c, &sA[idx * 8]);
        gl2lds16(Xj + (size_t)(j0 + r) * D + k + c, &sB[idx * 8]);
    }
}

// ---------------- row-normalize fp32 -> bf16 (one wave per row) ----------------
__global__ void norm_kernel(const float* __restrict__ X,
                            unsigned short* __restrict__ Xn, int D,
                            float* __restrict__ zero_me) {
    if (zero_me && blockIdx.x == 0 && threadIdx.x == 0) zero_me[0] = 0.0f;
    const int row  = blockIdx.x * 4 + (threadIdx.x >> 6);
    const int lane = threadIdx.x & 63;
    const float* xr = X + (size_t)row * D;
    float ss = 0.0f;
    for (int c = lane * 4; c < D; c += 256) {
        const floatx4 v = *(const floatx4*)(xr + c);
        ss += v[0] * v[0] + v[1] * v[1] + v[2] * v[2] + v[3] * v[3];
    }
    #pragma unroll
    for (int m = 32; m >= 1; m >>= 1) ss += __shfl_xor(ss, m);
    const float scale = 1.0f / fmaxf(sqrtf(ss), 1e-8f);
    unsigned short* outr = Xn + (size_t)row * D;
    for (int c = lane * 4; c < D; c += 256) {
        const floatx4 v = *(const floatx4*)(xr + c);
        us4 o;
        #pragma unroll
        for (int j = 0; j < 4; ++j) o.x[j] = f2bf(v[j] * scale);
        *(us4*)(outr + c) = o;
    }
}

// ---------------- fused dual-GEMM + softmax-stat tile kernel ----------------
// partials layout: [2*TJ][N][5] floats (Zt, V, UA, Zo, WB) per (slot,row)
// slot = tj*2 + wn  (each wn half-tile writes its own slot -> no cross-wave combine)
// Single 4x4 accumulator reused for both GEMMs; W=ea^3 parked bf16 in LDS
// (per-thread private, lane-interleaved -> conflict-free) between the loops.
// Register budget: ~92 VGPR + 64 AGPR ~= 156 -> 3 waves/SIMD -> 3 blocks/CU.
__launch_bounds__(256, 3)
__global__ void fused_kernel(const unsigned short* __restrict__ Xt,
                             const unsigned short* __restrict__ Xo,
                             float* __restrict__ partials) {
    __shared__ unsigned short sA[BM * 32];     // 8 KB
    __shared__ unsigned short sB[BN * 32];     // 8 KB
    __shared__ unsigned short sW[64 * 256];    // 32 KB: [idx 0..63][thread 0..255]

    const int t    = threadIdx.x;
    const int lane = t & 63;
    const int w    = t >> 6;
    const int wm   = w >> 1, wn = w & 1;
    const int lr   = lane & 15, lg = lane >> 4;

    // XCD-friendly swizzle (same as R1)
    const int bid = blockIdx.x;
    const int tj  = (bid & 7) | ((bid >> 9) << 3);
    const int ti  = (bid >> 3) & 63;
    const int i0  = ti * BM, j0 = tj * BN;

    floatx4 acc[4][4];
    #pragma unroll
    for (int a = 0; a < 4; ++a)
        #pragma unroll
        for (int b = 0; b < 4; ++b)
            acc[a][b] = (floatx4){0.0f, 0.0f, 0.0f, 0.0f};

    // ---- teacher GEMM: S_t tile, K = DT ----
    for (int k = 0; k < DT; k += 32) {
        stage_tile<DT>(Xt, Xt, sA, sB, i0, j0, k, t);
        asm volatile("s_waitcnt vmcnt(0)" ::: "memory");
        __syncthreads();
        short8 af[4], bf[4];
        #pragma unroll
        for (int mi = 0; mi < 4; ++mi)
            af[mi] = *(const short8*)&sA[(wm * 64 + mi * 16 + lr) * 32 + lg * 8];
        #pragma unroll
        for (int ni = 0; ni < 4; ++ni)
            bf[ni] = *(const short8*)&sB[(wn * 64 + ni * 16 + lr) * 32 + lg * 8];
        #pragma unroll
        for (int mi = 0; mi < 4; ++mi)
            #pragma unroll
            for (int ni = 0; ni < 4; ++ni)
                acc[mi][ni] = __builtin_amdgcn_mfma_f32_16x16x32_bf16(
                    af[mi], bf[ni], acc[mi][ni], 0, 0, 0);
        __syncthreads();
    }

    // ---- teacher epilogue: Zt, V, Sum(e3*a) per row; park W=e3 (bf16) in LDS ----
    // C/D layout: col = lane&15, row = (lane>>4)*4 + reg
    #pragma unroll
    for (int mi = 0; mi < 4; ++mi) {
        #pragma unroll
        for (int r = 0; r < 4; ++r) {
            const int row = wm * 64 + mi * 16 + lg * 4 + r;
            const int gi  = i0 + row;
            float zt = 0.0f, vv = 0.0f, ua = 0.0f;
            #pragma unroll
            for (int ni = 0; ni < 4; ++ni) {
                const int gj = j0 + wn * 64 + ni * 16 + lr;
                const float a = acc[mi][ni][r];
                float ea = __expf(a - 1.0f);
                if (gi == gj) ea = 0.0f;                   // diagonal -> prob 0
                const float e3 = ea * ea * ea;
                zt += ea; vv += e3; ua += e3 * a;
                sW[(mi * 16 + ni * 4 + r) * 256 + t] = f2bf(e3);
            }
            #pragma unroll
            for (int m = 8; m >= 1; m >>= 1) {
                zt += __shfl_xor(zt, m);
                vv += __shfl_xor(vv, m);
                ua += __shfl_xor(ua, m);
            }
            if (lr == 0) {
                float* p = partials + ((size_t)(tj * 2 + wn) * N + gi) * 5;
                p[0] = zt; p[1] = vv; p[2] = ua;
            }
        }
    }
    // No barrier needed: sW is per-thread private; sA/sB free to restage
    // (all reads of the last teacher tile completed before the final barrier).

    // ---- student GEMM: S_o tile, K = DO (same accumulator registers) ----
    #pragma unroll
    for (int a = 0; a < 4; ++a)
        #pragma unroll
        for (int b = 0; b < 4; ++b)
            acc[a][b] = (floatx4){0.0f, 0.0f, 0.0f, 0.0f};

    for (int k = 0; k < DO; k += 32) {
        stage_tile<DO>(Xo, Xo, sA, sB, i0, j0, k, t);
        asm volatile("s_waitcnt vmcnt(0)" ::: "memory");
        __syncthreads();
        short8 af[4], bf[4];
        #pragma unroll
        for (int mi = 0; mi < 4; ++mi)
            af[mi] = *(const short8*)&sA[(wm * 64 + mi * 16 + lr) * 32 + lg * 8];
        #pragma unroll
        for (int ni = 0; ni < 4; ++ni)
            bf[ni] = *(const short8*)&sB[(wn * 64 + ni * 16 + lr) * 32 + lg * 8];
        #pragma unroll
        for (int mi = 0; mi < 4; ++mi)
            #pragma unroll
            for (int ni = 0; ni < 4; ++ni)
                acc[mi][ni] = __builtin_amdgcn_mfma_f32_16x16x32_bf16(
                    af[mi], bf[ni], acc[mi][ni], 0, 0, 0);
        __syncthreads();
    }

    // ---- final epilogue: Zo, Sum(W*b) per row ----
    #pragma unroll
    for (int mi = 0; mi < 4; ++mi) {
        #pragma unroll
        for (int r = 0; r < 4; ++r) {
            const int row = wm * 64 + mi * 16 + lg * 4 + r;
            const int gi  = i0 + row;
            float zo = 0.0f, wb = 0.0f;
            #pragma unroll
            for (int ni = 0; ni < 4; ++ni) {
                const int gj = j0 + wn * 64 + ni * 16 + lr;
                const float b = acc[mi][ni][r];
                float eb = __expf(b - 1.0f);
                if (gi == gj) eb = 0.0f;
                const float wgt = bf2f(sW[(mi * 16 + ni * 4 + r) * 256 + t]);
                zo += eb; wb += wgt * b;   // diag: W==0 -> no contribution
            }
            #pragma unroll
            for (int m = 8; m >= 1; m >>= 1) {
                zo += __shfl_xor(zo, m);
                wb += __shfl_xor(wb, m);
            }
            if (lr == 0) {
                float* p = partials + ((size_t)(tj * 2 + wn) * N + gi) * 5;
                p[3] = zo; p[4] = wb;
            }
        }
    }
}

// ---------------- final per-row combine + scalar reduce ----------------
__global__ void reduce_kernel(const float* __restrict__ partials,
                              float* __restrict__ out) {
    const int i = blockIdx.x * 256 + threadIdx.x;   // row
    float zt = 0.0f, vv = 0.0f, ua = 0.0f, zo = 0.0f, wb = 0.0f;
    for (int jb = 0; jb < 2 * TJ; ++jb) {
        const float* p = partials + ((size_t)jb * N + i) * 5;
        zt += p[0]; vv += p[1]; ua += p[2]; zo += p[3]; wb += p[4];
    }
    // loss_i = (U + V*log(Zo/Zt)) / Zt^3, U = ua - wb
    float li = (ua - wb + vv * __logf(zo / zt)) / (zt * zt * zt);
    #pragma unroll
    for (int m = 32; m >= 1; m >>= 1) li += __shfl_xor(li, m);
    __shared__ float wsh[4];
    const int w = threadIdx.x >> 6;
    if ((threadIdx.x & 63) == 0) wsh[w] = li;
    __syncthreads();
    if (threadIdx.x == 0) {
        const float s = (wsh[0] + wsh[1] + wsh[2] + wsh[3]) *
                        (1.0f / ((float)N * (float)N));   // WEIGHT=1, mean over N^2
        atomicAdd(out, s);
    }
}

extern "C" void kernel_launch(void* const* d_in, const int* in_sizes, int n_in,
                              void* d_out, int out_size, void* d_ws, size_t ws_size,
                              hipStream_t stream) {
    (void)in_sizes; (void)n_in; (void)out_size; (void)ws_size;
    const float* mo = (const float*)d_in[0];   // model_output [8192,512] fp32
    const float* tg = (const float*)d_in[1];   // targets      [8192,768] fp32
    float* out = (float*)d_out;

    char* ws = (char*)d_ws;
    unsigned short* Xt = (unsigned short*)ws;                          // 12.58 MB
    unsigned short* Xo = (unsigned short*)(ws + (size_t)N * DT * 2);   //  8.39 MB
    float* partials    = (float*)(ws + (size_t)N * DT * 2 + (size_t)N * DO * 2);
    // partials: 128 * 8192 * 5 * 4 B = 20.97 MB; total ws use ~41.9 MB

    norm_kernel<<<N / 4, 256, 0, stream>>>(tg, Xt, DT, out);   // also zeroes out
    norm_kernel<<<N / 4, 256, 0, stream>>>(mo, Xo, DO, nullptr);
    fused_kernel<<<TI * TJ, 256, 0, stream>>>(Xt, Xo, partials);
    reduce_kernel<<<N / 256, 256, 0, stream>>>(partials, out);
}